// Round 8
// baseline (146.590 us; speedup 1.0000x reference)
//
#include <hip/hip_runtime.h>

// NTN: out[n,k] = relu( cos(x1 @ W1[k], x2 @ W2[k]) + [x1,x2]·V[k] + b[k] )
// N=32768, D=128, K=16.
// R8: 32x32x16 MFMA, 64 rows/wave (2 tiles of 32) -> halves LDS-read bytes/CU
// vs R3/R7 (the dominant floor: 4 MB -> 2 MB/CU). Fragment layouts verified by
// R4 (passed). Register plan: launch_bounds(256,1) (R5's spill = (256,2) cap),
// part2 in its own kernel (main RMWs out) so main carries only xb(128)+C(64).
// Grid 512 = (rb 0..127: 256 rows) x (kh 0..3: k-range 4); 2 blocks/CU.
// Chunk cc = k*4 + q4 (16KB): both sides of one 32-e tile, 8 d-slices of 16.
// Per chunk: accumulate a1/a2 over s, fold into nm/q1/q2 (in-lane 16-reg fold;
// cross-half via one shfl_xor(32) per k). All array indexing static (R4 lesson).

typedef __attribute__((ext_vector_type(8))) __bf16 bf16x8;
typedef __attribute__((ext_vector_type(8))) unsigned short us8;
typedef __attribute__((ext_vector_type(16))) float f32x16;

static __device__ __forceinline__ unsigned short f2bf(float f) {
  unsigned u = __float_as_uint(f);
  u += 0x7FFFu + ((u >> 16) & 1u);   // round-to-nearest-even
  return (unsigned short)(u >> 16);
}

static __device__ __forceinline__ bf16x8 as_bf(us8 u) {
  bf16x8 r;
  __builtin_memcpy(&r, &u, sizeof(r));
  return r;
}

// ---------------- prep: coalesced transpose-swizzle ----------------
// wsW: 64 chunks (cc = k*4 + q4) of 1024 16B-units (16KB).
//   unit-in-chunk: side*512 + s*64 + lane  (s = d-slice 0..7)
//   frag[j] = W_side[k][d = s*16 + (lane>>5)*8 + j][e = q4*32 + (lane&31)]
// wsV: unit cs*64+lane (cs 0..15):
//   frag[j] = (lane&31)<16 ? V[lane&31][c = cs*16 + (lane>>5)*8 + j] : 0
// Grid: 65 blocks. 0..63: (k=b>>2, side=(b>>1)&1, h=b&1) covering e-half h.
__global__ void ntn_prep(const float* __restrict__ W1, const float* __restrict__ W2,
                         const float* __restrict__ V,
                         unsigned short* __restrict__ wsW, unsigned short* __restrict__ wsV) {
  const int t = threadIdx.x;
  const int blk = blockIdx.x;
  if (blk == 64) {   // V: 1024 us8 units
    const int lane = t & 63, hh = (t >> 5) & 1, l31 = t & 31;
#pragma unroll
    for (int ui = 0; ui < 4; ++ui) {
      int u = ui * 256 + t;          // 0..1023
      int cs = u >> 6;
      us8 r;
      if (l31 < 16) {
        const float* src = V + l31 * 256 + cs * 16 + hh * 8;
#pragma unroll
        for (int j = 0; j < 8; ++j) r[j] = f2bf(src[j]);
      } else {
#pragma unroll
        for (int j = 0; j < 8; ++j) r[j] = 0;
      }
      (void)lane;
      *(us8*)(wsV + (size_t)u * 8) = r;
    }
    return;
  }

  __shared__ float T[128 * 68];
  const int k = blk >> 2, side = (blk >> 1) & 1, h = blk & 1;
  const float* W = (side ? W2 : W1) + k * 16384 + h * 64;

  // load 128 d-rows x 64 e-cols, coalesced float4
#pragma unroll
  for (int i = 0; i < 8; ++i) {
    int fidx = i * 256 + t;          // 0..2047
    int d = fidx >> 4, c4 = fidx & 15;
    float4 v = *(const float4*)(W + d * 128 + c4 * 4);
    *(float4*)&T[d * 68 + c4 * 4] = v;
  }
  __syncthreads();

  // emit 1024 us8 units: u: lane=u&63, s=(u>>6)&7, q4l=(u>>9)&1
#pragma unroll
  for (int ui = 0; ui < 4; ++ui) {
    int u = ui * 256 + t;
    int lane = u & 63, s = (u >> 6) & 7, q4l = (u >> 9) & 1;
    int hh = lane >> 5, l31 = lane & 31;
    int d0 = s * 16 + hh * 8;
    int el = q4l * 32 + l31;         // e - h*64
    us8 r;
#pragma unroll
    for (int j = 0; j < 8; ++j) r[j] = f2bf(T[(d0 + j) * 68 + el]);
    int cc = k * 4 + h * 2 + q4l;
    int uic = side * 512 + s * 64 + lane;
    *(us8*)(wsW + ((size_t)cc * 1024 + uic) * 8) = r;
  }
}

// ---------------- part2: out[n,k] = x_cat[n]·V[k] + b[k] (no relu) ----------------
// 128 blocks x 256 thr; wave covers 64 rows (2 tiles of 32).
__global__ __launch_bounds__(256, 1) void ntn_part2(
    const float* __restrict__ x1, const float* __restrict__ x2,
    const float* __restrict__ b, const unsigned short* __restrict__ wsV,
    float* __restrict__ out) {
  const int tid = threadIdx.x;
  const int lane = tid & 63, wave = tid >> 6;
  const int hh = lane >> 5, l31 = lane & 31;
  const int rowbase = blockIdx.x * 256 + wave * 64;
  const f32x16 zero16 = {0.f};

#pragma unroll
  for (int nt = 0; nt < 2; ++nt) {
    const int row = rowbase + nt * 32 + l31;
    f32x16 c = zero16;
#pragma unroll
    for (int cs = 0; cs < 16; ++cs) {
      const float* xp = (cs < 8) ? (x1 + (size_t)row * 128 + cs * 16 + hh * 8)
                                 : (x2 + (size_t)row * 128 + (cs - 8) * 16 + hh * 8);
      float4 v0 = *(const float4*)xp;
      float4 v1 = *(const float4*)(xp + 4);
      us8 uu;
      uu[0] = f2bf(v0.x); uu[1] = f2bf(v0.y); uu[2] = f2bf(v0.z); uu[3] = f2bf(v0.w);
      uu[4] = f2bf(v1.x); uu[5] = f2bf(v1.y); uu[6] = f2bf(v1.z); uu[7] = f2bf(v1.w);
      bf16x8 vf = as_bf(*(const us8*)(wsV + (size_t)(cs * 64 + lane) * 8));
      c = __builtin_amdgcn_mfma_f32_32x32x16_bf16(vf, as_bf(uu), c, 0, 0, 0);
    }
#pragma unroll
    for (int r = 0; r < 8; ++r) {          // m = (r&3)+8*(r>>2)+4*hh = k (0..15)
      int k = (r & 3) + 8 * (r >> 2) + 4 * hh;
      out[(size_t)row * 16 + k] = c[r] + b[k];
    }
  }
}

// ---------------- main ----------------
__global__ __launch_bounds__(256, 1) void ntn_main(
    const float* __restrict__ x1, const float* __restrict__ x2,
    const unsigned short* __restrict__ wsW, float* __restrict__ out) {
  __shared__ uint4 ldsW[2][1024];   // two 16KB chunk slots = 32KB

  const int tid = threadIdx.x;
  const int lane = tid & 63, wave = tid >> 6;
  const int hh = lane >> 5, l31 = lane & 31;
  const int kh = blockIdx.x & 3;          // k range [4kh, 4kh+4)
  const int rb = blockIdx.x >> 2;         // 256-row group
  const int rowbase = rb * 256 + wave * 64;

  const f32x16 zero16 = {0.f};

  // stage one 16KB chunk: 4 glds x (64 lanes x 16B) per wave
  auto stage = [&](int cc, int slot) {
    const unsigned short* src = wsW + (size_t)cc * 8192 + (size_t)(wave * 256 + lane) * 8;
    uint4* dst = &ldsW[slot][wave * 256];
#pragma unroll
    for (int i = 0; i < 4; ++i)
      __builtin_amdgcn_global_load_lds(
          (__attribute__((address_space(1))) void*)(void*)(src + i * 512),
          (__attribute__((address_space(3))) void*)(dst + i * 64), 16, 0, 0);
  };

  const int cbase = kh * 16;
  stage(cbase, 0);

  // ---- X fragments (B-operand): frag[j] = X[rowbase+nt*32+l31][s*16 + hh*8 + j] ----
  bf16x8 xb[2][2][8];   // [side][nt][s] = 128 VGPRs
#pragma unroll
  for (int side = 0; side < 2; ++side) {
    const float* xp0 = side ? x2 : x1;
#pragma unroll
    for (int nt = 0; nt < 2; ++nt) {
#pragma unroll
      for (int s = 0; s < 8; ++s) {
        const float* p = xp0 + (size_t)(rowbase + nt * 32 + l31) * 128 + s * 16 + hh * 8;
        float4 v0 = *(const float4*)p;
        float4 v1 = *(const float4*)(p + 4);
        us8 uu;
        uu[0] = f2bf(v0.x); uu[1] = f2bf(v0.y); uu[2] = f2bf(v0.z); uu[3] = f2bf(v0.w);
        uu[4] = f2bf(v1.x); uu[5] = f2bf(v1.y); uu[6] = f2bf(v1.z); uu[7] = f2bf(v1.w);
        xb[side][nt][s] = as_bf(uu);
      }
    }
  }

  float nm[2] = {0.f, 0.f}, q1[2] = {0.f, 0.f}, q2[2] = {0.f, 0.f};

  // one chunk = one 32-e tile, both sides: accumulate over 8 d-slices, fold
  auto compute = [&](int slot) {
    f32x16 a1[2] = {zero16, zero16}, a2[2] = {zero16, zero16};
#pragma unroll
    for (int s = 0; s < 8; ++s) {
      bf16x8 wa = as_bf(*(const us8*)&ldsW[slot][s * 64 + lane]);
      bf16x8 wb = as_bf(*(const us8*)&ldsW[slot][512 + s * 64 + lane]);
#pragma unroll
      for (int nt = 0; nt < 2; ++nt) {
        a1[nt] = __builtin_amdgcn_mfma_f32_32x32x16_bf16(wa, xb[0][nt][s], a1[nt], 0, 0, 0);
        a2[nt] = __builtin_amdgcn_mfma_f32_32x32x16_bf16(wb, xb[1][nt][s], a2[nt], 0, 0, 0);
      }
    }
#pragma unroll
    for (int nt = 0; nt < 2; ++nt) {
      float n = 0.f, s1 = 0.f, s2 = 0.f;
#pragma unroll
      for (int r = 0; r < 16; ++r) {
        n  += a1[nt][r] * a2[nt][r];
        s1 += a1[nt][r] * a1[nt][r];
        s2 += a2[nt][r] * a2[nt][r];
      }
      nm[nt] += n; q1[nt] += s1; q2[nt] += s2;
    }
  };

#pragma unroll 1
  for (int kk = 0; kk < 4; ++kk) {
#pragma unroll
    for (int q4 = 0; q4 < 4; ++q4) {
      const int c = kk * 4 + q4;           // 0..15
      __syncthreads();                     // chunk c arrived in slot c&1
      if (c < 15) stage(cbase + c + 1, (c + 1) & 1);
      compute(c & 1);
    }

    const int k = kh * 4 + kk;
#pragma unroll
    for (int nt = 0; nt < 2; ++nt) {
      float n = nm[nt], s1 = q1[nt], s2 = q2[nt];
      n  += __shfl_xor(n, 32);
      s1 += __shfl_xor(s1, 32);
      s2 += __shfl_xor(s2, 32);
      float d1 = fmaxf(sqrtf(s1), 1e-8f);
      float d2 = fmaxf(sqrtf(s2), 1e-8f);
      float p1 = n / (d1 * d2);
      if (hh == 0) {
        float* po = out + (size_t)(rowbase + nt * 32 + l31) * 16 + k;
        *po = fmaxf(*po + p1, 0.f);        // *po = part2 + b (from ntn_part2)
      }
      nm[nt] = 0.f; q1[nt] = 0.f; q2[nt] = 0.f;
    }
  }
}

extern "C" void kernel_launch(void* const* d_in, const int* in_sizes, int n_in,
                              void* d_out, int out_size, void* d_ws, size_t ws_size,
                              hipStream_t stream) {
  const float* x1 = (const float*)d_in[0];
  const float* x2 = (const float*)d_in[1];
  const float* W1 = (const float*)d_in[2];
  const float* W2 = (const float*)d_in[3];
  const float* V  = (const float*)d_in[4];
  const float* b  = (const float*)d_in[5];
  float* out = (float*)d_out;
  unsigned short* wsW = (unsigned short*)d_ws;
  unsigned short* wsV = wsW + (size_t)65536 * 8;   // 1MB offset

  ntn_prep<<<65, 256, 0, stream>>>(W1, W2, V, wsW, wsV);
  ntn_part2<<<128, 256, 0, stream>>>(x1, x2, b, wsV, out);
  ntn_main<<<512, 256, 0, stream>>>(x1, x2, wsW, out);
}